// Round 9
// baseline (149.443 us; speedup 1.0000x reference)
//
#include <hip/hip_runtime.h>
#include <hip/hip_bf16.h>
#include <stdint.h>

typedef unsigned short u16;

#define B_  4
#define LQ  2048
#define LK  4096
#define D_  1024
#define DC  512
#define EPSF 1e-6f

typedef __bf16 bf16x8 __attribute__((ext_vector_type(8)));
typedef float  f32x4  __attribute__((ext_vector_type(4)));

// ---------- helpers ----------
__device__ __forceinline__ u16 f2bf(float f) {
    uint32_t u = __float_as_uint(f);
    uint32_t r = (u + 0x7FFFu + ((u >> 16) & 1u)) >> 16;  // RNE
    return (u16)r;
}
__device__ __forceinline__ float bf2f(u16 h) {
    return __uint_as_float(((uint32_t)h) << 16);
}
__device__ __forceinline__ void gload_lds16(const void* g, void* l) {
    __builtin_amdgcn_global_load_lds(
        (const __attribute__((address_space(1))) uint32_t*)g,
        (__attribute__((address_space(3))) uint32_t*)l, 16, 0, 0);
}

// ---------- fused prep: W->Wt hi/lo | w_s | codes->bf16+kcb ----------
#define NB_WT  ((D_ / 64) * (DC / 64))   // 128
#define NB_WS  4
#define NB_DQ2 4096                      // 4 code-rows per block

__global__ void prep_all(const float* __restrict__ w, u16* __restrict__ wth,
                         u16* __restrict__ wtl, float* __restrict__ partS,
                         const int* __restrict__ kc, const float* __restrict__ scale,
                         const float* __restrict__ zero, u16* __restrict__ codeb,
                         u16* __restrict__ kcb) {
    __shared__ float t[64][65];
    __shared__ float red[4];
    const int bid = blockIdx.x;
    const int tid = threadIdx.x;

    if (bid < NB_WT) {
        // ---- prep_wt: W (D x Dc) -> W^T hi/lo bf16 (Dc x D) ----
        int b2 = bid;
        int d0 = (b2 % (D_ / 64)) * 64, c0 = (b2 / (D_ / 64)) * 64;
        int tx = tid & 15, ty = tid >> 4;
        #pragma unroll
        for (int r = 0; r < 4; r++) {
            float4 v = *reinterpret_cast<const float4*>(&w[(size_t)(d0 + ty + r * 16) * DC + c0 + tx * 4]);
            t[ty + r * 16][tx * 4 + 0] = v.x;
            t[ty + r * 16][tx * 4 + 1] = v.y;
            t[ty + r * 16][tx * 4 + 2] = v.z;
            t[ty + r * 16][tx * 4 + 3] = v.w;
        }
        __syncthreads();
        #pragma unroll
        for (int r = 0; r < 4; r++) {
            int c = c0 + ty + r * 16;
            ushort4 h, l;
            float v0 = t[tx * 4 + 0][ty + r * 16];
            float v1 = t[tx * 4 + 1][ty + r * 16];
            float v2 = t[tx * 4 + 2][ty + r * 16];
            float v3 = t[tx * 4 + 3][ty + r * 16];
            h.x = f2bf(v0); l.x = f2bf(v0 - bf2f(h.x));
            h.y = f2bf(v1); l.y = f2bf(v1 - bf2f(h.y));
            h.z = f2bf(v2); l.z = f2bf(v2 - bf2f(h.z));
            h.w = f2bf(v3); l.w = f2bf(v3 - bf2f(h.w));
            *reinterpret_cast<ushort4*>(&wth[(size_t)c * D_ + d0 + tx * 4]) = h;
            *reinterpret_cast<ushort4*>(&wtl[(size_t)c * D_ + d0 + tx * 4]) = l;
        }
    } else if (bid < NB_WT + NB_WS) {
        // ---- w_s: partial sums of S = sum_d (rowsum W_d)^2 ----
        int b2 = bid - NB_WT;
        int d = b2 * 256 + tid;
        const float4* row = reinterpret_cast<const float4*>(w + (size_t)d * DC);
        float u = 0.f;
        #pragma unroll 8
        for (int i = 0; i < DC / 4; i++) { float4 v = row[i]; u += v.x + v.y + v.z + v.w; }
        float p = u * u;
        #pragma unroll
        for (int off = 32; off; off >>= 1) p += __shfl_down(p, off);
        if ((tid & 63) == 0) red[tid >> 6] = p;
        __syncthreads();
        if (tid == 0) partS[b2] = red[0] + red[1] + red[2] + red[3];
    } else {
        // ---- codes -> exact bf16 + bf16 kc = scale*(code-zero), 4 rows/block ----
        int row = (bid - NB_WT - NB_WS) * 4 + (tid >> 6);
        int ln = tid & 63;
        float sc = scale[row], z = zero[row];
        const int2* src = reinterpret_cast<const int2*>(kc + (size_t)row * DC);
        ushort2* dc = reinterpret_cast<ushort2*>(codeb + (size_t)row * DC);
        ushort2* dk = reinterpret_cast<ushort2*>(kcb + (size_t)row * DC);
        #pragma unroll
        for (int c = 0; c < 4; c++) {
            int2 v = src[c * 64 + ln];
            ushort2 cb, kb;
            cb.x = f2bf((float)v.x);
            cb.y = f2bf((float)v.y);
            kb.x = f2bf(sc * ((float)v.x - z));
            kb.y = f2bf(sc * ((float)v.y - z));
            dc[c * 64 + ln] = cb;
            dk[c * 64 + ln] = kb;
        }
    }
}

// ---------- fused: G = W^T W (16 blocks) | q_proj = q @ W (256 blocks) ----------
// qproj reads f32 q directly (reg-staged A, inline bf16 cvt) and computes qsq.
__global__ __launch_bounds__(256, 2) void gemm_gq(const u16* __restrict__ Wth,
                                                  const u16* __restrict__ Wtl,
                                                  u16* __restrict__ Gh,
                                                  u16* __restrict__ Gl,
                                                  const float* __restrict__ Qf,
                                                  u16* __restrict__ Cq,
                                                  float* __restrict__ qsq) {
    __shared__ u16 smem[4][128 * 32];
    const int tid = threadIdx.x;
    const int wid = tid >> 6, lane = tid & 63;
    const int lr = lane & 15, lk = lane >> 4;
    const int wr = wid >> 1, wc = wid & 1;
    const int srow = tid >> 2;
    const int scol = (tid & 3) * 8;

    if (blockIdx.x < 16) {
        // ======== G = Wt @ Wt^T, split-bf16 3-pass, hi/lo bf16 out ========
        const int m0 = (blockIdx.x & 3) * 128, n0 = (blockIdx.x >> 2) * 128;
        const int K = D_;
        f32x4 acc[4][4] = {};
        const size_t gA = (size_t)(m0 + srow) * K + scol;
        const size_t gB = (size_t)(n0 + srow) * K + scol;
        char* ashb = (char*)(&smem[0][0]) + (wid << 10);
        char* aslb = (char*)(&smem[1][0]) + (wid << 10);
        char* bshb = (char*)(&smem[2][0]) + (wid << 10);
        char* bslb = (char*)(&smem[3][0]) + (wid << 10);

        for (int k0 = 0; k0 < K; k0 += 32) {
            gload_lds16(Wth + gA + k0, ashb);
            gload_lds16(Wth + gA + k0 + (size_t)64 * K, ashb + 4096);
            gload_lds16(Wtl + gA + k0, aslb);
            gload_lds16(Wtl + gA + k0 + (size_t)64 * K, aslb + 4096);
            gload_lds16(Wth + gB + k0, bshb);
            gload_lds16(Wth + gB + k0 + (size_t)64 * K, bshb + 4096);
            gload_lds16(Wtl + gB + k0, bslb);
            gload_lds16(Wtl + gB + k0 + (size_t)64 * K, bslb + 4096);
            __syncthreads();
            bf16x8 afh[4], afl[4], bfh[4], bfl[4];
            #pragma unroll
            for (int i = 0; i < 4; i++) {
                int off = (wr * 64 + i * 16 + lr) * 32 + lk * 8;
                afh[i] = *reinterpret_cast<const bf16x8*>(&smem[0][off]);
                afl[i] = *reinterpret_cast<const bf16x8*>(&smem[1][off]);
            }
            #pragma unroll
            for (int j = 0; j < 4; j++) {
                int off = (wc * 64 + j * 16 + lr) * 32 + lk * 8;
                bfh[j] = *reinterpret_cast<const bf16x8*>(&smem[2][off]);
                bfl[j] = *reinterpret_cast<const bf16x8*>(&smem[3][off]);
            }
            #pragma unroll
            for (int i = 0; i < 4; i++)
                #pragma unroll
                for (int j = 0; j < 4; j++) {
                    acc[i][j] = __builtin_amdgcn_mfma_f32_16x16x32_bf16(afh[i], bfh[j], acc[i][j], 0, 0, 0);
                    acc[i][j] = __builtin_amdgcn_mfma_f32_16x16x32_bf16(afh[i], bfl[j], acc[i][j], 0, 0, 0);
                    acc[i][j] = __builtin_amdgcn_mfma_f32_16x16x32_bf16(afl[i], bfh[j], acc[i][j], 0, 0, 0);
                }
            __syncthreads();
        }
        #pragma unroll
        for (int i = 0; i < 4; i++) {
            int row = m0 + wr * 64 + i * 16 + lk * 4;
            #pragma unroll
            for (int j = 0; j < 4; j++) {
                int col = n0 + wc * 64 + j * 16 + lr;
                #pragma unroll
                for (int r = 0; r < 4; r++) {
                    float v = acc[i][j][r];
                    u16 h = f2bf(v);
                    Gh[(size_t)(row + r) * DC + col] = h;
                    Gl[(size_t)(row + r) * DC + col] = f2bf(v - bf2f(h));
                }
            }
        }
    } else {
        // ======== q_proj = q(f32) @ W (M=8192, N=512, K=1024) ========
        const int q2 = blockIdx.x - 16;
        const int m0 = (q2 & 63) * 128, n0 = (q2 >> 6) * 128;
        const int K = D_;
        const int NT = K / 32;
        f32x4 acc[4][4] = {};
        const float* aq = Qf + (size_t)(m0 + srow) * K + (tid & 3) * 8;
        const u16* bg = Wth + (size_t)(n0 + srow) * K + scol;
        float sq0 = 0.f, sq1 = 0.f;
        float4 a0, a1, a2, a3;

        #define LOADA(kt) do {                                                 \
            const float4* p0 = reinterpret_cast<const float4*>(aq + (kt) * 32);\
            const float4* p1 = reinterpret_cast<const float4*>(                \
                aq + (size_t)64 * K + (kt) * 32);                              \
            a0 = p0[0]; a1 = p0[1]; a2 = p1[0]; a3 = p1[1];                    \
        } while (0)

        #define WRITEA(buf) do {                                               \
            bf16x8 v0, v1;                                                     \
            v0[0] = (__bf16)a0.x; v0[1] = (__bf16)a0.y;                        \
            v0[2] = (__bf16)a0.z; v0[3] = (__bf16)a0.w;                        \
            v0[4] = (__bf16)a1.x; v0[5] = (__bf16)a1.y;                        \
            v0[6] = (__bf16)a1.z; v0[7] = (__bf16)a1.w;                        \
            v1[0] = (__bf16)a2.x; v1[1] = (__bf16)a2.y;                        \
            v1[2] = (__bf16)a2.z; v1[3] = (__bf16)a2.w;                        \
            v1[4] = (__bf16)a3.x; v1[5] = (__bf16)a3.y;                        \
            v1[6] = (__bf16)a3.z; v1[7] = (__bf16)a3.w;                        \
            *reinterpret_cast<bf16x8*>(&smem[(buf)][wid * 512 + lane * 8]) = v0; \
            *reinterpret_cast<bf16x8*>(&smem[(buf)][wid * 512 + lane * 8 + 2048]) = v1; \
            sq0 += a0.x * a0.x + a0.y * a0.y + a0.z * a0.z + a0.w * a0.w       \
                 + a1.x * a1.x + a1.y * a1.y + a1.z * a1.z + a1.w * a1.w;      \
            sq1 += a2.x * a2.x + a2.y * a2.y + a2.z * a2.z + a2.w * a2.w       \
                 + a3.x * a3.x + a3.y * a3.y + a3.z * a3.z + a3.w * a3.w;      \
        } while (0)

        #define STAGEB(buf, kt) do {                                           \
            char* bsb_ = (char*)(&smem[2 + (buf)][0]) + (wid << 10);           \
            gload_lds16(bg + (kt) * 32, bsb_);                                 \
            gload_lds16(bg + (kt) * 32 + (size_t)64 * K, bsb_ + 4096);         \
        } while (0)

        #define COMPUTE_P(buf) do {                                            \
            bf16x8 af[4], bfr[4];                                              \
            _Pragma("unroll")                                                  \
            for (int i = 0; i < 4; i++)                                        \
                af[i] = *reinterpret_cast<const bf16x8*>(                      \
                    &smem[(buf)][(wr * 64 + i * 16 + lr) * 32 + lk * 8]);      \
            _Pragma("unroll")                                                  \
            for (int j = 0; j < 4; j++)                                        \
                bfr[j] = *reinterpret_cast<const bf16x8*>(                     \
                    &smem[2 + (buf)][(wc * 64 + j * 16 + lr) * 32 + lk * 8]);  \
            asm volatile("s_waitcnt lgkmcnt(0)" ::: "memory");                 \
            __builtin_amdgcn_sched_barrier(0);                                 \
            _Pragma("unroll")                                                  \
            for (int i = 0; i < 4; i++)                                        \
                _Pragma("unroll")                                              \
                for (int j = 0; j < 4; j++)                                    \
                    acc[i][j] = __builtin_amdgcn_mfma_f32_16x16x32_bf16(       \
                        af[i], bfr[j], acc[i][j], 0, 0, 0);                    \
        } while (0)

        LOADA(0);
        STAGEB(0, 0);
        WRITEA(0);
        __syncthreads();
        int cur = 0;
        for (int t = 0; t < NT - 1; ++t) {
            LOADA(t + 1);               // issue next A loads (f32, to regs)
            STAGEB(cur ^ 1, t + 1);     // issue next B gload_lds
            COMPUTE_P(cur);             // ds_read + MFMA current
            WRITEA(cur ^ 1);            // cvt+write next A (waits A regs only)
            __syncthreads();            // drains vmcnt+lgkm, barrier
            cur ^= 1;
        }
        COMPUTE_P(cur);
        #undef LOADA
        #undef WRITEA
        #undef STAGEB
        #undef COMPUTE_P

        // qsq: exact f32 row sums (pre-cvt values); n0==0 blocks only
        sq0 += __shfl_xor(sq0, 1); sq0 += __shfl_xor(sq0, 2);
        sq1 += __shfl_xor(sq1, 1); sq1 += __shfl_xor(sq1, 2);
        if ((tid & 3) == 0 && q2 < 64) {
            qsq[m0 + srow] = sq0;
            qsq[m0 + 64 + srow] = sq1;
        }

        #pragma unroll
        for (int i = 0; i < 4; i++) {
            int row = m0 + wr * 64 + i * 16 + lk * 4;
            #pragma unroll
            for (int j = 0; j < 4; j++) {
                int col = n0 + wc * 64 + j * 16 + lr;
                #pragma unroll
                for (int r = 0; r < 4; r++)
                    Cq[(size_t)(row + r) * DC + col] = f2bf(acc[i][j][r]);
            }
        }
    }
}

// ---------- codeG = code @ G (2-pass hi/lo) + quadratic-form partials ----------
// 1D grid 512, T1 XCD swizzle, 3-deep counted-vmcnt pipeline (T3/T4).
__global__ __launch_bounds__(256, 2) void gemm_ksq(const u16* __restrict__ A,
                                                   const u16* __restrict__ Bh,
                                                   const u16* __restrict__ Bl,
                                                   float* __restrict__ part1,
                                                   float* __restrict__ part2) {
    __shared__ u16 As[3][128 * 32];
    __shared__ u16 Bsh[3][128 * 32];
    __shared__ u16 Bsl[3][128 * 32];
    const int wg = (blockIdx.x & 7) * 64 + (blockIdx.x >> 3);   // 512 -> bijective
    const int m0 = (wg & 127) * 128, n0 = (wg >> 7) * 128;
    const int tid = threadIdx.x;
    const int wid = tid >> 6, lane = tid & 63;
    const int lr = lane & 15, lk = lane >> 4;
    const int wr = wid >> 1, wc = wid & 1;
    const int K = DC;
    const int NT = K / 32;                      // 16

    f32x4 acc[4][4] = {};
    const int srow = tid >> 2;
    const int scol = (tid & 3) * 8;
    const u16* ag = A + (size_t)(m0 + srow) * K + scol;
    const u16* bhg = Bh + (size_t)(n0 + srow) * K + scol;
    const u16* blg = Bl + (size_t)(n0 + srow) * K + scol;

    #define STAGE_K(buf, kt) do {                                          \
        char* asb_  = (char*)(&As[(buf)][0]) + (wid << 10);                \
        char* bshb_ = (char*)(&Bsh[(buf)][0]) + (wid << 10);               \
        char* bslb_ = (char*)(&Bsl[(buf)][0]) + (wid << 10);               \
        int k0_ = (kt) * 32;                                               \
        gload_lds16(ag + k0_, asb_);                                       \
        gload_lds16(ag + k0_ + (size_t)64 * K, asb_ + 4096);               \
        gload_lds16(bhg + k0_, bshb_);                                     \
        gload_lds16(bhg + k0_ + (size_t)64 * K, bshb_ + 4096);             \
        gload_lds16(blg + k0_, bslb_);                                     \
        gload_lds16(blg + k0_ + (size_t)64 * K, bslb_ + 4096);             \
    } while (0)

    #define COMPUTE_K(buf) do {                                            \
        bf16x8 af[4], bh_[4], bl_[4];                                      \
        _Pragma("unroll")                                                  \
        for (int i = 0; i < 4; i++)                                        \
            af[i] = *reinterpret_cast<const bf16x8*>(                      \
                &As[(buf)][(wr * 64 + i * 16 + lr) * 32 + lk * 8]);        \
        _Pragma("unroll")                                                  \
        for (int j = 0; j < 4; j++) {                                      \
            int off = (wc * 64 + j * 16 + lr) * 32 + lk * 8;               \
            bh_[j] = *reinterpret_cast<const bf16x8*>(&Bsh[(buf)][off]);   \
            bl_[j] = *reinterpret_cast<const bf16x8*>(&Bsl[(buf)][off]);   \
        }                                                                  \
        asm volatile("s_waitcnt lgkmcnt(0)" ::: "memory");                 \
        __builtin_amdgcn_sched_barrier(0);                                 \
        _Pragma("unroll")                                                  \
        for (int i = 0; i < 4; i++)                                        \
            _Pragma("unroll")                                              \
            for (int j = 0; j < 4; j++) {                                  \
                acc[i][j] = __builtin_amdgcn_mfma_f32_16x16x32_bf16(       \
                    af[i], bh_[j], acc[i][j], 0, 0, 0);                    \
                acc[i][j] = __builtin_amdgcn_mfma_f32_16x16x32_bf16(       \
                    af[i], bl_[j], acc[i][j], 0, 0, 0);                    \
            }                                                              \
    } while (0)

    STAGE_K(0, 0);
    STAGE_K(1, 1);
    asm volatile("s_waitcnt vmcnt(6)" ::: "memory");
    __builtin_amdgcn_s_barrier();
    int cur = 0;
    for (int t = 0; t < NT - 2; ++t) {
        int nx = cur + 2; if (nx >= 3) nx -= 3;
        STAGE_K(nx, t + 2);
        COMPUTE_K(cur);
        asm volatile("s_waitcnt vmcnt(6)" ::: "memory");
        __builtin_amdgcn_s_barrier();
        cur = (cur + 1 == 3) ? 0 : cur + 1;
    }
    COMPUTE_K(cur);
    asm volatile("s_waitcnt vmcnt(0)" ::: "memory");
    __builtin_amdgcn_s_barrier();
    cur = (cur + 1 == 3) ? 0 : cur + 1;
    COMPUTE_K(cur);
    #undef STAGE_K
    #undef COMPUTE_K

    #pragma unroll
    for (int i = 0; i < 4; i++) {
        #pragma unroll
        for (int r = 0; r < 4; r++) {
            int row = m0 + wr * 64 + i * 16 + lk * 4 + r;
            float p1 = 0.f, p2 = 0.f;
            #pragma unroll
            for (int j = 0; j < 4; j++) {
                int col = n0 + wc * 64 + j * 16 + lr;
                float cg = acc[i][j][r];
                float cd = bf2f(A[(size_t)row * DC + col]);
                p1 = fmaf(cg, cd, p1);
                p2 += cg;
            }
            #pragma unroll
            for (int m = 1; m <= 8; m <<= 1) {
                p1 += __shfl_xor(p1, m);
                p2 += __shfl_xor(p2, m);
            }
            if (lr == 0) {
                size_t idx = (size_t)row * 8 + (wg >> 7) * 2 + wc;
                part1[idx] = p1;
                part2[idx] = p2;
            }
        }
    }
}

// ---------- cross = q_proj @ kc^T + fused ksq-reduce + Poincare epilogue ----------
__global__ __launch_bounds__(256, 2) void gemm_dist2(const u16* __restrict__ Qp,
                                                     const u16* __restrict__ Kc,
                                                     const float* __restrict__ qsq,
                                                     const float* __restrict__ part1,
                                                     const float* __restrict__ part2,
                                                     const float* __restrict__ partS,
                                                     const float* __restrict__ kscale,
                                                     const float* __restrict__ kzero,
                                                     float* __restrict__ out) {
    const int wgid = (blockIdx.x & 7) * 256 + (blockIdx.x >> 3);
    const int bx = wgid & 15, by = (wgid >> 4) & 31, bz = wgid >> 9;

    const u16* A  = Qp + (size_t)bz * LQ * DC;
    const u16* Bt = Kc + (size_t)bz * LK * DC;
    float* O = out + (size_t)bz * LQ * LK;
    const float* qs_ = qsq + bz * LQ;

    __shared__ u16 As[3][128 * 32];
    __shared__ u16 Bs[3][128 * 32];
    __shared__ float kss[128];
    const int tid = threadIdx.x;
    const int wid = tid >> 6, lane = tid & 63;
    const int lr = lane & 15, lk = lane >> 4;
    const int wr = wid >> 1, wc = wid & 1;
    const int m0 = bx * 128, n0 = by * 128;
    const int K = DC;
    const int NT = K / 32;

    if (tid < 128) {
        int gcol = bz * LK + n0 + tid;
        const float4* p1 = reinterpret_cast<const float4*>(part1 + (size_t)gcol * 8);
        const float4* p2 = reinterpret_cast<const float4*>(part2 + (size_t)gcol * 8);
        float4 a0 = p1[0], a1 = p1[1];
        float4 b0 = p2[0], b1 = p2[1];
        float P1 = a0.x + a0.y + a0.z + a0.w + a1.x + a1.y + a1.z + a1.w;
        float P2 = b0.x + b0.y + b0.z + b0.w + b1.x + b1.y + b1.z + b1.w;
        float S = partS[0] + partS[1] + partS[2] + partS[3];
        float sc = kscale[gcol], z = kzero[gcol];
        kss[tid] = sc * sc * (P1 - 2.f * z * P2 + z * z * S);
    }

    f32x4 acc[4][4] = {};
    const int srow = tid >> 2;
    const int scol = (tid & 3) * 8;
    const u16* ag = A + (size_t)(m0 + srow) * K + scol;
    const u16* bg = Bt + (size_t)(n0 + srow) * K + scol;

    #define STAGE_D(buf, kt) do {                                          \
        char* asb_ = (char*)(&As[(buf)][0]) + (wid << 10);                 \
        char* bsb_ = (char*)(&Bs[(buf)][0]) + (wid << 10);                 \
        int k0_ = (kt) * 32;                                               \
        gload_lds16(ag + k0_, asb_);                                       \
        gload_lds16(ag + k0_ + (size_t)64 * K, asb_ + 4096);               \
        gload_lds16(bg + k0_, bsb_);                                       \
        gload_lds16(bg + k0_ + (size_t)64 * K, bsb_ + 4096);               \
    } while (0)

    #define COMPUTE_D(buf) do {                                            \
        bf16x8 af[4], bfr[4];                                              \
        _Pragma("unroll")                                                  \
        for (int i = 0; i < 4; i++)                                        \
            af[i] = *reinterpret_cast<const bf16x8*>(                      \
                &As[(buf)][(wr * 64 + i * 16 + lr) * 32 + lk * 8]);        \
        _Pragma("unroll")                                                  \
        for (int j = 0; j < 4; j++)                                        \
            bfr[j] = *reinterpret_cast<const bf16x8*>(                     \
                &Bs[(buf)][(wc * 64 + j * 16 + lr) * 32 + lk * 8]);        \
        asm volatile("s_waitcnt lgkmcnt(0)" ::: "memory");                 \
        __builtin_amdgcn_sched_barrier(0);                                 \
        _Pragma("unroll")                                                  \
        for (int i = 0; i < 4; i++)                                        \
            _Pragma("unroll")                                              \
            for (int j = 0; j < 4; j++)                                    \
                acc[i][j] = __builtin_amdgcn_mfma_f32_16x16x32_bf16(       \
                    af[i], bfr[j], acc[i][j], 0, 0, 0);                    \
    } while (0)

    STAGE_D(0, 0);
    STAGE_D(1, 1);
    asm volatile("s_waitcnt vmcnt(4)" ::: "memory");
    __builtin_amdgcn_s_barrier();
    int cur = 0;
    for (int t = 0; t < NT - 2; ++t) {
        int nx = cur + 2; if (nx >= 3) nx -= 3;
        STAGE_D(nx, t + 2);
        COMPUTE_D(cur);
        asm volatile("s_waitcnt vmcnt(4)" ::: "memory");
        __builtin_amdgcn_s_barrier();
        cur = (cur + 1 == 3) ? 0 : cur + 1;
    }
    COMPUTE_D(cur);
    asm volatile("s_waitcnt vmcnt(0)" ::: "memory");
    __builtin_amdgcn_s_barrier();
    cur = (cur + 1 == 3) ? 0 : cur + 1;
    COMPUTE_D(cur);
    #undef STAGE_D
    #undef COMPUTE_D

    const float LN2 = 0.69314718055994531f;
    float ksv[4], pkv[4];
    #pragma unroll
    for (int j = 0; j < 4; j++) {
        ksv[j] = kss[wc * 64 + j * 16 + lr];
        pkv[j] = 1.f - fminf(ksv[j], 1.f - EPSF);
    }
    #pragma unroll
    for (int i = 0; i < 4; i++) {
        int row = m0 + wr * 64 + i * 16 + lk * 4;
        #pragma unroll
        for (int r = 0; r < 4; r++) {
            int gr = row + r;
            float qs = qs_[gr];
            float pq = 1.f - fminf(qs, 1.f - EPSF);
            float* orow = O + (size_t)gr * LK + n0 + wc * 64 + lr;
            #pragma unroll
            for (int j = 0; j < 4; j++) {
                float d = fmaxf(fmaf(acc[i][j][r], -2.f, qs + ksv[j]), 0.f);
                float den = fmaf(pq, pkv[j], EPSF);
                float u = (d + d) * __builtin_amdgcn_rcpf(den);
                float s = __builtin_amdgcn_sqrtf(u * (u + 2.f));
                orow[j * 16] = LN2 * __builtin_amdgcn_logf(1.f + u + s);
            }
        }
    }
}

// ---------- launcher ----------
extern "C" void kernel_launch(void* const* d_in, const int* in_sizes, int n_in,
                              void* d_out, int out_size, void* d_ws, size_t ws_size,
                              hipStream_t stream) {
    const float* q      = (const float*)d_in[0];
    const int*   kcmp   = (const int*)d_in[1];
    const float* wup    = (const float*)d_in[2];
    const float* kscale = (const float*)d_in[3];
    const float* kzero  = (const float*)d_in[4];
    float* out = (float*)d_out;

    char* ws = (char*)d_ws;
    u16*   qp    = (u16*)(ws);                       // 8 MiB
    u16*   codeb = (u16*)(ws + 8388608);             // 16 MiB
    u16*   kcb   = (u16*)(ws + 25165824);            // 16 MiB
    u16*   wth   = (u16*)(ws + 41943040);            // 1 MiB
    u16*   wtl   = (u16*)(ws + 42991616);            // 1 MiB
    u16*   gh    = (u16*)(ws + 44040192);            // 0.5 MiB
    u16*   gl    = (u16*)(ws + 44564480);            // 0.5 MiB
    float* qsq   = (float*)(ws + 45088768);          // 32 KiB
    float* part1 = (float*)(ws + 45121536);          // 512 KiB
    float* part2 = (float*)(ws + 45645824);          // 512 KiB
    float* partS = (float*)(ws + 46170112);          // 16 B

    prep_all<<<NB_WT + NB_WS + NB_DQ2, 256, 0, stream>>>(
        wup, wth, wtl, partS, kcmp, kscale, kzero, codeb, kcb);

    gemm_gq<<<16 + 256, 256, 0, stream>>>(wth, wtl, gh, gl, q, qp, qsq);

    gemm_ksq<<<512, 256, 0, stream>>>(codeb, gh, gl, part1, part2);

    gemm_dist2<<<2048, 256, 0, stream>>>(qp, kcb, qsq, part1, part2, partS,
                                         kscale, kzero, out);
}

// Round 10
// 138.140 us; speedup vs baseline: 1.0818x; 1.0818x over previous
//
#include <hip/hip_runtime.h>
#include <hip/hip_bf16.h>
#include <stdint.h>

typedef unsigned short u16;

#define B_  4
#define LQ  2048
#define LK  4096
#define D_  1024
#define DC  512
#define EPSF 1e-6f

typedef __bf16 bf16x8 __attribute__((ext_vector_type(8)));
typedef float  f32x4  __attribute__((ext_vector_type(4)));

// ---------- helpers ----------
__device__ __forceinline__ u16 f2bf(float f) {
    uint32_t u = __float_as_uint(f);
    uint32_t r = (u + 0x7FFFu + ((u >> 16) & 1u)) >> 16;  // RNE
    return (u16)r;
}
__device__ __forceinline__ float bf2f(u16 h) {
    return __uint_as_float(((uint32_t)h) << 16);
}
__device__ __forceinline__ void gload_lds16(const void* g, void* l) {
    __builtin_amdgcn_global_load_lds(
        (const __attribute__((address_space(1))) uint32_t*)g,
        (__attribute__((address_space(3))) uint32_t*)l, 16, 0, 0);
}

// ---------- fused prep: q->bf16+qsq | W->Wt hi/lo | w_s | codes->bf16+kcb ----------
#define NB_Q2  2048                      // 4 q-rows per block
#define NB_WT  ((D_ / 64) * (DC / 64))   // 128
#define NB_WS  4
#define NB_DQ2 4096                      // 4 code-rows per block

__global__ void prep_all(const float* __restrict__ q, u16* __restrict__ qb,
                         float* __restrict__ qsq,
                         const float* __restrict__ w, u16* __restrict__ wth,
                         u16* __restrict__ wtl, float* __restrict__ partS,
                         const int* __restrict__ kc, const float* __restrict__ scale,
                         const float* __restrict__ zero, u16* __restrict__ codeb,
                         u16* __restrict__ kcb) {
    __shared__ float t[64][65];
    __shared__ float red[4];
    const int bid = blockIdx.x;
    const int tid = threadIdx.x;

    if (bid < NB_Q2) {
        // ---- prep_q: 4 rows/block, bf16 convert + exact f32 row sumsq ----
        int row = bid * 4 + (tid >> 6);
        int ln = tid & 63;
        const float4* qr = reinterpret_cast<const float4*>(q + (size_t)row * D_);
        ushort4* ob = reinterpret_cast<ushort4*>(qb + (size_t)row * D_);
        float s = 0.f;
        #pragma unroll
        for (int c = 0; c < 4; c++) {
            float4 v = qr[c * 64 + ln];
            ushort4 o;
            o.x = f2bf(v.x); o.y = f2bf(v.y); o.z = f2bf(v.z); o.w = f2bf(v.w);
            ob[c * 64 + ln] = o;
            s += v.x * v.x + v.y * v.y + v.z * v.z + v.w * v.w;
        }
        #pragma unroll
        for (int off = 32; off; off >>= 1) s += __shfl_down(s, off);
        if (ln == 0) qsq[row] = s;
    } else if (bid < NB_Q2 + NB_WT) {
        // ---- prep_wt: W (D x Dc) -> W^T hi/lo bf16 (Dc x D) ----
        int b2 = bid - NB_Q2;
        int d0 = (b2 % (D_ / 64)) * 64, c0 = (b2 / (D_ / 64)) * 64;
        int tx = tid & 15, ty = tid >> 4;
        #pragma unroll
        for (int r = 0; r < 4; r++) {
            float4 v = *reinterpret_cast<const float4*>(&w[(size_t)(d0 + ty + r * 16) * DC + c0 + tx * 4]);
            t[ty + r * 16][tx * 4 + 0] = v.x;
            t[ty + r * 16][tx * 4 + 1] = v.y;
            t[ty + r * 16][tx * 4 + 2] = v.z;
            t[ty + r * 16][tx * 4 + 3] = v.w;
        }
        __syncthreads();
        #pragma unroll
        for (int r = 0; r < 4; r++) {
            int c = c0 + ty + r * 16;
            ushort4 h, l;
            float v0 = t[tx * 4 + 0][ty + r * 16];
            float v1 = t[tx * 4 + 1][ty + r * 16];
            float v2 = t[tx * 4 + 2][ty + r * 16];
            float v3 = t[tx * 4 + 3][ty + r * 16];
            h.x = f2bf(v0); l.x = f2bf(v0 - bf2f(h.x));
            h.y = f2bf(v1); l.y = f2bf(v1 - bf2f(h.y));
            h.z = f2bf(v2); l.z = f2bf(v2 - bf2f(h.z));
            h.w = f2bf(v3); l.w = f2bf(v3 - bf2f(h.w));
            *reinterpret_cast<ushort4*>(&wth[(size_t)c * D_ + d0 + tx * 4]) = h;
            *reinterpret_cast<ushort4*>(&wtl[(size_t)c * D_ + d0 + tx * 4]) = l;
        }
    } else if (bid < NB_WT + NB_Q2 + NB_WS) {
        // ---- w_s: partial sums of S = sum_d (rowsum W_d)^2 ----
        int b2 = bid - NB_Q2 - NB_WT;
        int d = b2 * 256 + tid;
        const float4* row = reinterpret_cast<const float4*>(w + (size_t)d * DC);
        float u = 0.f;
        #pragma unroll 8
        for (int i = 0; i < DC / 4; i++) { float4 v = row[i]; u += v.x + v.y + v.z + v.w; }
        float p = u * u;
        #pragma unroll
        for (int off = 32; off; off >>= 1) p += __shfl_down(p, off);
        if ((tid & 63) == 0) red[tid >> 6] = p;
        __syncthreads();
        if (tid == 0) partS[b2] = red[0] + red[1] + red[2] + red[3];
    } else {
        // ---- codes -> exact bf16 + bf16 kc, 4 rows/block, int4 loads ----
        int row = (bid - NB_Q2 - NB_WT - NB_WS) * 4 + (tid >> 6);
        int ln = tid & 63;
        float sc = scale[row], z = zero[row];
        const int4* src = reinterpret_cast<const int4*>(kc + (size_t)row * DC);
        ushort4* dc = reinterpret_cast<ushort4*>(codeb + (size_t)row * DC);
        ushort4* dk = reinterpret_cast<ushort4*>(kcb + (size_t)row * DC);
        #pragma unroll
        for (int c = 0; c < 2; c++) {
            int4 v = src[c * 64 + ln];
            ushort4 cb, kb;
            cb.x = f2bf((float)v.x); cb.y = f2bf((float)v.y);
            cb.z = f2bf((float)v.z); cb.w = f2bf((float)v.w);
            kb.x = f2bf(sc * ((float)v.x - z)); kb.y = f2bf(sc * ((float)v.y - z));
            kb.z = f2bf(sc * ((float)v.z - z)); kb.w = f2bf(sc * ((float)v.w - z));
            dc[c * 64 + ln] = cb;
            dk[c * 64 + ln] = kb;
        }
    }
}

// ---------- fused: G split-K partials (64 blocks) | q_proj (256 blocks) ----------
__global__ __launch_bounds__(256, 2) void gemm_gq(const u16* __restrict__ Wth,
                                                  const u16* __restrict__ Wtl,
                                                  float* __restrict__ gp,
                                                  const u16* __restrict__ Q,
                                                  u16* __restrict__ Cq) {
    __shared__ u16 smem[4][128 * 32];
    const int tid = threadIdx.x;
    const int wid = tid >> 6, lane = tid & 63;
    const int lr = lane & 15, lk = lane >> 4;
    const int wr = wid >> 1, wc = wid & 1;
    const int srow = tid >> 2;
    const int scol = (tid & 3) * 8;

    if (blockIdx.x < 64) {
        // ==== G partial: tile t (0..15), K-split s (0..3) of 256 cols ====
        const int t = blockIdx.x >> 2, s = blockIdx.x & 3;
        const int m0 = (t & 3) * 128, n0 = (t >> 2) * 128;
        const int K = D_;
        f32x4 acc[4][4] = {};
        const size_t gA = (size_t)(m0 + srow) * K + scol;
        const size_t gB = (size_t)(n0 + srow) * K + scol;
        char* ashb = (char*)(&smem[0][0]) + (wid << 10);
        char* aslb = (char*)(&smem[1][0]) + (wid << 10);
        char* bshb = (char*)(&smem[2][0]) + (wid << 10);
        char* bslb = (char*)(&smem[3][0]) + (wid << 10);

        for (int k0 = s * 256; k0 < s * 256 + 256; k0 += 32) {
            gload_lds16(Wth + gA + k0, ashb);
            gload_lds16(Wth + gA + k0 + (size_t)64 * K, ashb + 4096);
            gload_lds16(Wtl + gA + k0, aslb);
            gload_lds16(Wtl + gA + k0 + (size_t)64 * K, aslb + 4096);
            gload_lds16(Wth + gB + k0, bshb);
            gload_lds16(Wth + gB + k0 + (size_t)64 * K, bshb + 4096);
            gload_lds16(Wtl + gB + k0, bslb);
            gload_lds16(Wtl + gB + k0 + (size_t)64 * K, bslb + 4096);
            __syncthreads();
            bf16x8 afh[4], afl[4], bfh[4], bfl[4];
            #pragma unroll
            for (int i = 0; i < 4; i++) {
                int off = (wr * 64 + i * 16 + lr) * 32 + lk * 8;
                afh[i] = *reinterpret_cast<const bf16x8*>(&smem[0][off]);
                afl[i] = *reinterpret_cast<const bf16x8*>(&smem[1][off]);
            }
            #pragma unroll
            for (int j = 0; j < 4; j++) {
                int off = (wc * 64 + j * 16 + lr) * 32 + lk * 8;
                bfh[j] = *reinterpret_cast<const bf16x8*>(&smem[2][off]);
                bfl[j] = *reinterpret_cast<const bf16x8*>(&smem[3][off]);
            }
            #pragma unroll
            for (int i = 0; i < 4; i++)
                #pragma unroll
                for (int j = 0; j < 4; j++) {
                    acc[i][j] = __builtin_amdgcn_mfma_f32_16x16x32_bf16(afh[i], bfh[j], acc[i][j], 0, 0, 0);
                    acc[i][j] = __builtin_amdgcn_mfma_f32_16x16x32_bf16(afh[i], bfl[j], acc[i][j], 0, 0, 0);
                    acc[i][j] = __builtin_amdgcn_mfma_f32_16x16x32_bf16(afl[i], bfh[j], acc[i][j], 0, 0, 0);
                }
            __syncthreads();
        }
        float* dst = gp + (size_t)s * (DC * DC);
        #pragma unroll
        for (int i = 0; i < 4; i++) {
            int row = m0 + wr * 64 + i * 16 + lk * 4;
            #pragma unroll
            for (int j = 0; j < 4; j++) {
                int col = n0 + wc * 64 + j * 16 + lr;
                #pragma unroll
                for (int r = 0; r < 4; r++)
                    dst[(size_t)(row + r) * DC + col] = acc[i][j][r];
            }
        }
    } else {
        // ==== q_proj = q @ W (M=8192, N=512, K=1024), dbuf ====
        const int q2 = blockIdx.x - 64;
        const int m0 = (q2 & 63) * 128, n0 = (q2 >> 6) * 128;
        const int K = D_;
        const int NT = K / 32;
        f32x4 acc[4][4] = {};
        const u16* ag = Q + (size_t)(m0 + srow) * K + scol;
        const u16* bg = Wth + (size_t)(n0 + srow) * K + scol;

        #define STAGE_P(buf, kt) do {                                          \
            char* asb_ = (char*)(&smem[(buf)][0]) + (wid << 10);               \
            char* bsb_ = (char*)(&smem[2 + (buf)][0]) + (wid << 10);           \
            int k0_ = (kt) * 32;                                               \
            gload_lds16(ag + k0_, asb_);                                       \
            gload_lds16(ag + k0_ + (size_t)64 * K, asb_ + 4096);               \
            gload_lds16(bg + k0_, bsb_);                                       \
            gload_lds16(bg + k0_ + (size_t)64 * K, bsb_ + 4096);               \
        } while (0)

        #define COMPUTE_P(buf) do {                                            \
            bf16x8 af[4], bfr[4];                                              \
            _Pragma("unroll")                                                  \
            for (int i = 0; i < 4; i++)                                        \
                af[i] = *reinterpret_cast<const bf16x8*>(                      \
                    &smem[(buf)][(wr * 64 + i * 16 + lr) * 32 + lk * 8]);      \
            _Pragma("unroll")                                                  \
            for (int j = 0; j < 4; j++)                                        \
                bfr[j] = *reinterpret_cast<const bf16x8*>(                     \
                    &smem[2 + (buf)][(wc * 64 + j * 16 + lr) * 32 + lk * 8]);  \
            asm volatile("s_waitcnt lgkmcnt(0)" ::: "memory");                 \
            __builtin_amdgcn_sched_barrier(0);                                 \
            _Pragma("unroll")                                                  \
            for (int i = 0; i < 4; i++)                                        \
                _Pragma("unroll")                                              \
                for (int j = 0; j < 4; j++)                                    \
                    acc[i][j] = __builtin_amdgcn_mfma_f32_16x16x32_bf16(       \
                        af[i], bfr[j], acc[i][j], 0, 0, 0);                    \
        } while (0)

        STAGE_P(0, 0);
        asm volatile("s_waitcnt vmcnt(0)" ::: "memory");
        __builtin_amdgcn_s_barrier();
        int cur = 0;
        for (int t = 0; t < NT - 1; ++t) {
            STAGE_P(cur ^ 1, t + 1);
            COMPUTE_P(cur);
            asm volatile("s_waitcnt vmcnt(0)" ::: "memory");
            __builtin_amdgcn_s_barrier();
            cur ^= 1;
        }
        COMPUTE_P(cur);
        #undef STAGE_P
        #undef COMPUTE_P

        #pragma unroll
        for (int i = 0; i < 4; i++) {
            int row = m0 + wr * 64 + i * 16 + lk * 4;
            #pragma unroll
            for (int j = 0; j < 4; j++) {
                int col = n0 + wc * 64 + j * 16 + lr;
                #pragma unroll
                for (int r = 0; r < 4; r++)
                    Cq[(size_t)(row + r) * DC + col] = f2bf(acc[i][j][r]);
            }
        }
    }
}

// ---------- g_reduce: sum 4 split partials -> Gh/Gl bf16 ----------
__global__ void g_reduce(const float* __restrict__ gp, u16* __restrict__ Gh,
                         u16* __restrict__ Gl) {
    int i = (blockIdx.x * 256 + threadIdx.x) * 4;
    float4 a = *reinterpret_cast<const float4*>(gp + i);
    float4 b = *reinterpret_cast<const float4*>(gp + (DC * DC) + i);
    float4 c = *reinterpret_cast<const float4*>(gp + 2 * (DC * DC) + i);
    float4 d = *reinterpret_cast<const float4*>(gp + 3 * (DC * DC) + i);
    float v0 = a.x + b.x + c.x + d.x;
    float v1 = a.y + b.y + c.y + d.y;
    float v2 = a.z + b.z + c.z + d.z;
    float v3 = a.w + b.w + c.w + d.w;
    ushort4 h, l;
    h.x = f2bf(v0); l.x = f2bf(v0 - bf2f(h.x));
    h.y = f2bf(v1); l.y = f2bf(v1 - bf2f(h.y));
    h.z = f2bf(v2); l.z = f2bf(v2 - bf2f(h.z));
    h.w = f2bf(v3); l.w = f2bf(v3 - bf2f(h.w));
    *reinterpret_cast<ushort4*>(Gh + i) = h;
    *reinterpret_cast<ushort4*>(Gl + i) = l;
}

// ---------- codeG = code @ G (2-pass hi/lo) + quadratic-form partials ----------
// 1D grid 512, T1 XCD swizzle, 3-deep counted-vmcnt pipeline (T3/T4).
__global__ __launch_bounds__(256, 2) void gemm_ksq(const u16* __restrict__ A,
                                                   const u16* __restrict__ Bh,
                                                   const u16* __restrict__ Bl,
                                                   float* __restrict__ part1,
                                                   float* __restrict__ part2) {
    __shared__ u16 As[3][128 * 32];
    __shared__ u16 Bsh[3][128 * 32];
    __shared__ u16 Bsl[3][128 * 32];
    const int wg = (blockIdx.x & 7) * 64 + (blockIdx.x >> 3);   // 512 -> bijective
    const int m0 = (wg & 127) * 128, n0 = (wg >> 7) * 128;
    const int tid = threadIdx.x;
    const int wid = tid >> 6, lane = tid & 63;
    const int lr = lane & 15, lk = lane >> 4;
    const int wr = wid >> 1, wc = wid & 1;
    const int K = DC;
    const int NT = K / 32;                      // 16

    f32x4 acc[4][4] = {};
    const int srow = tid >> 2;
    const int scol = (tid & 3) * 8;
    const u16* ag = A + (size_t)(m0 + srow) * K + scol;
    const u16* bhg = Bh + (size_t)(n0 + srow) * K + scol;
    const u16* blg = Bl + (size_t)(n0 + srow) * K + scol;

    #define STAGE_K(buf, kt) do {                                          \
        char* asb_  = (char*)(&As[(buf)][0]) + (wid << 10);                \
        char* bshb_ = (char*)(&Bsh[(buf)][0]) + (wid << 10);               \
        char* bslb_ = (char*)(&Bsl[(buf)][0]) + (wid << 10);               \
        int k0_ = (kt) * 32;                                               \
        gload_lds16(ag + k0_, asb_);                                       \
        gload_lds16(ag + k0_ + (size_t)64 * K, asb_ + 4096);               \
        gload_lds16(bhg + k0_, bshb_);                                     \
        gload_lds16(bhg + k0_ + (size_t)64 * K, bshb_ + 4096);             \
        gload_lds16(blg + k0_, bslb_);                                     \
        gload_lds16(blg + k0_ + (size_t)64 * K, bslb_ + 4096);             \
    } while (0)

    #define COMPUTE_K(buf) do {                                            \
        bf16x8 af[4], bh_[4], bl_[4];                                      \
        _Pragma("unroll")                                                  \
        for (int i = 0; i < 4; i++)                                        \
            af[i] = *reinterpret_cast<const bf16x8*>(                      \
                &As[(buf)][(wr * 64 + i * 16 + lr) * 32 + lk * 8]);        \
        _Pragma("unroll")                                                  \
        for (int j = 0; j < 4; j++) {                                      \
            int off = (wc * 64 + j * 16 + lr) * 32 + lk * 8;               \
            bh_[j] = *reinterpret_cast<const bf16x8*>(&Bsh[(buf)][off]);   \
            bl_[j] = *reinterpret_cast<const bf16x8*>(&Bsl[(buf)][off]);   \
        }                                                                  \
        asm volatile("s_waitcnt lgkmcnt(0)" ::: "memory");                 \
        __builtin_amdgcn_sched_barrier(0);                                 \
        _Pragma("unroll")                                                  \
        for (int i = 0; i < 4; i++)                                        \
            _Pragma("unroll")                                              \
            for (int j = 0; j < 4; j++) {                                  \
                acc[i][j] = __builtin_amdgcn_mfma_f32_16x16x32_bf16(       \
                    af[i], bh_[j], acc[i][j], 0, 0, 0);                    \
                acc[i][j] = __builtin_amdgcn_mfma_f32_16x16x32_bf16(       \
                    af[i], bl_[j], acc[i][j], 0, 0, 0);                    \
            }                                                              \
    } while (0)

    STAGE_K(0, 0);
    STAGE_K(1, 1);
    asm volatile("s_waitcnt vmcnt(6)" ::: "memory");
    __builtin_amdgcn_s_barrier();
    int cur = 0;
    for (int t = 0; t < NT - 2; ++t) {
        int nx = cur + 2; if (nx >= 3) nx -= 3;
        STAGE_K(nx, t + 2);
        COMPUTE_K(cur);
        asm volatile("s_waitcnt vmcnt(6)" ::: "memory");
        __builtin_amdgcn_s_barrier();
        cur = (cur + 1 == 3) ? 0 : cur + 1;
    }
    COMPUTE_K(cur);
    asm volatile("s_waitcnt vmcnt(0)" ::: "memory");
    __builtin_amdgcn_s_barrier();
    cur = (cur + 1 == 3) ? 0 : cur + 1;
    COMPUTE_K(cur);
    #undef STAGE_K
    #undef COMPUTE_K

    #pragma unroll
    for (int i = 0; i < 4; i++) {
        #pragma unroll
        for (int r = 0; r < 4; r++) {
            int row = m0 + wr * 64 + i * 16 + lk * 4 + r;
            float p1 = 0.f, p2 = 0.f;
            #pragma unroll
            for (int j = 0; j < 4; j++) {
                int col = n0 + wc * 64 + j * 16 + lr;
                float cg = acc[i][j][r];
                float cd = bf2f(A[(size_t)row * DC + col]);
                p1 = fmaf(cg, cd, p1);
                p2 += cg;
            }
            #pragma unroll
            for (int m = 1; m <= 8; m <<= 1) {
                p1 += __shfl_xor(p1, m);
                p2 += __shfl_xor(p2, m);
            }
            if (lr == 0) {
                size_t idx = (size_t)row * 8 + (wg >> 7) * 2 + wc;
                part1[idx] = p1;
                part2[idx] = p2;
            }
        }
    }
}

// ---------- cross = q_proj @ kc^T + fused ksq-reduce + Poincare epilogue ----------
__global__ __launch_bounds__(256, 2) void gemm_dist2(const u16* __restrict__ Qp,
                                                     const u16* __restrict__ Kc,
                                                     const float* __restrict__ qsq,
                                                     const float* __restrict__ part1,
                                                     const float* __restrict__ part2,
                                                     const float* __restrict__ partS,
                                                     const float* __restrict__ kscale,
                                                     const float* __restrict__ kzero,
                                                     float* __restrict__ out) {
    const int wgid = (blockIdx.x & 7) * 256 + (blockIdx.x >> 3);
    const int bx = wgid & 15, by = (wgid >> 4) & 31, bz = wgid >> 9;

    const u16* A  = Qp + (size_t)bz * LQ * DC;
    const u16* Bt = Kc + (size_t)bz * LK * DC;
    float* O = out + (size_t)bz * LQ * LK;
    const float* qs_ = qsq + bz * LQ;

    __shared__ u16 As[3][128 * 32];
    __shared__ u16 Bs[3][128 * 32];
    __shared__ float kss[128];
    const int tid = threadIdx.x;
    const int wid = tid >> 6, lane = tid & 63;
    const int lr = lane & 15, lk = lane >> 4;
    const int wr = wid >> 1, wc = wid & 1;
    const int m0 = bx * 128, n0 = by * 128;
    const int K = DC;
    const int NT = K / 32;

    if (tid < 128) {
        int gcol = bz * LK + n0 + tid;
        const float4* p1 = reinterpret_cast<const float4*>(part1 + (size_t)gcol * 8);
        const float4* p2 = reinterpret_cast<const float4*>(part2 + (size_t)gcol * 8);
        float4 a0 = p1[0], a1 = p1[1];
        float4 b0 = p2[0], b1 = p2[1];
        float P1 = a0.x + a0.y + a0.z + a0.w + a1.x + a1.y + a1.z + a1.w;
        float P2 = b0.x + b0.y + b0.z + b0.w + b1.x + b1.y + b1.z + b1.w;
        float S = partS[0] + partS[1] + partS[2] + partS[3];
        float sc = kscale[gcol], z = kzero[gcol];
        kss[tid] = sc * sc * (P1 - 2.f * z * P2 + z * z * S);
    }

    f32x4 acc[4][4] = {};
    const int srow = tid >> 2;
    const int scol = (tid & 3) * 8;
    const u16* ag = A + (size_t)(m0 + srow) * K + scol;
    const u16* bg = Bt + (size_t)(n0 + srow) * K + scol;

    #define STAGE_D(buf, kt) do {                                          \
        char* asb_ = (char*)(&As[(buf)][0]) + (wid << 10);                 \
        char* bsb_ = (char*)(&Bs[(buf)][0]) + (wid << 10);                 \
        int k0_ = (kt) * 32;                                               \
        gload_lds16(ag + k0_, asb_);                                       \
        gload_lds16(ag + k0_ + (size_t)64 * K, asb_ + 4096);               \
        gload_lds16(bg + k0_, bsb_);                                       \
        gload_lds16(bg + k0_ + (size_t)64 * K, bsb_ + 4096);               \
    } while (0)

    #define COMPUTE_D(buf) do {                                            \
        bf16x8 af[4], bfr[4];                                              \
        _Pragma("unroll")                                                  \
        for (int i = 0; i < 4; i++)                                        \
            af[i] = *reinterpret_cast<const bf16x8*>(                      \
                &As[(buf)][(wr * 64 + i * 16 + lr) * 32 + lk * 8]);        \
        _Pragma("unroll")                                                  \
        for (int j = 0; j < 4; j++)                                        \
            bfr[j] = *reinterpret_cast<const bf16x8*>(                     \
                &Bs[(buf)][(wc * 64 + j * 16 + lr) * 32 + lk * 8]);        \
        asm volatile("s_waitcnt lgkmcnt(0)" ::: "memory");                 \
        __builtin_amdgcn_sched_barrier(0);                                 \
        _Pragma("unroll")                                                  \
        for (int i = 0; i < 4; i++)                                        \
            _Pragma("unroll")                                              \
            for (int j = 0; j < 4; j++)                                    \
                acc[i][j] = __builtin_amdgcn_mfma_f32_16x16x32_bf16(       \
                    af[i], bfr[j], acc[i][j], 0, 0, 0);                    \
    } while (0)

    STAGE_D(0, 0);
    STAGE_D(1, 1);
    asm volatile("s_waitcnt vmcnt(4)" ::: "memory");
    __builtin_amdgcn_s_barrier();
    int cur = 0;
    for (int t = 0; t < NT - 2; ++t) {
        int nx = cur + 2; if (nx >= 3) nx -= 3;
        STAGE_D(nx, t + 2);
        COMPUTE_D(cur);
        asm volatile("s_waitcnt vmcnt(4)" ::: "memory");
        __builtin_amdgcn_s_barrier();
        cur = (cur + 1 == 3) ? 0 : cur + 1;
    }
    COMPUTE_D(cur);
    asm volatile("s_waitcnt vmcnt(0)" ::: "memory");
    __builtin_amdgcn_s_barrier();
    cur = (cur + 1 == 3) ? 0 : cur + 1;
    COMPUTE_D(cur);
    #undef STAGE_D
    #undef COMPUTE_D

    const float LN2 = 0.69314718055994531f;
    float ksv[4], pkv[4];
    #pragma unroll
    for (int j = 0; j < 4; j++) {
        ksv[j] = kss[wc * 64 + j * 16 + lr];
        pkv[j] = 1.f - fminf(ksv[j], 1.f - EPSF);
    }
    #pragma unroll
    for (int i = 0; i < 4; i++) {
        int row = m0 + wr * 64 + i * 16 + lk * 4;
        #pragma unroll
        for (int r = 0; r < 4; r++) {
            int gr = row + r;
            float qs = qs_[gr];
            float pq = 1.f - fminf(qs, 1.f - EPSF);
            float* orow = O + (size_t)gr * LK + n0 + wc * 64 + lr;
            #pragma unroll
            for (int j = 0; j < 4; j++) {
                float d = fmaxf(fmaf(acc[i][j][r], -2.f, qs + ksv[j]), 0.f);
                float den = fmaf(pq, pkv[j], EPSF);
                float u = (d + d) * __builtin_amdgcn_rcpf(den);
                float s = __builtin_amdgcn_sqrtf(u * (u + 2.f));
                orow[j * 16] = LN2 * __builtin_amdgcn_logf(1.f + u + s);
            }
        }
    }
}

// ---------- launcher ----------
extern "C" void kernel_launch(void* const* d_in, const int* in_sizes, int n_in,
                              void* d_out, int out_size, void* d_ws, size_t ws_size,
                              hipStream_t stream) {
    const float* q      = (const float*)d_in[0];
    const int*   kcmp   = (const int*)d_in[1];
    const float* wup    = (const float*)d_in[2];
    const float* kscale = (const float*)d_in[3];
    const float* kzero  = (const float*)d_in[4];
    float* out = (float*)d_out;

    char* ws = (char*)d_ws;
    u16*   qb    = (u16*)(ws);                       // 16 MiB
    u16*   qp    = (u16*)(ws + 16777216);            // 8 MiB
    u16*   codeb = (u16*)(ws + 25165824);            // 16 MiB
    u16*   kcb   = (u16*)(ws + 41943040);            // 16 MiB
    u16*   wth   = (u16*)(ws + 58720256);            // 1 MiB
    u16*   wtl   = (u16*)(ws + 59768832);            // 1 MiB
    u16*   gh    = (u16*)(ws + 60817408);            // 0.5 MiB
    u16*   gl    = (u16*)(ws + 61341696);            // 0.5 MiB
    float* qsq   = (float*)(ws + 61865984);          // 32 KiB
    float* part1 = (float*)(ws + 61898752);          // 512 KiB
    float* part2 = (float*)(ws + 62423040);          // 512 KiB
    float* partS = (float*)(ws + 62947328);          // 16 B
    float* gp    = (float*)(ws + 62947344);          // 4 MiB (4 x 512x512 f32)

    prep_all<<<NB_Q2 + NB_WT + NB_WS + NB_DQ2, 256, 0, stream>>>(
        q, qb, qsq, wup, wth, wtl, partS, kcmp, kscale, kzero, qb == nullptr ? nullptr : (u16*)codeb, kcb);

    gemm_gq<<<64 + 256, 256, 0, stream>>>(wth, wtl, gp, qb, qp);

    g_reduce<<<DC * DC / 1024, 256, 0, stream>>>(gp, gh, gl);

    gemm_ksq<<<512, 256, 0, stream>>>(codeb, gh, gl, part1, part2);

    gemm_dist2<<<2048, 256, 0, stream>>>(qp, kcb, qsq, part1, part2, partS,
                                         kscale, kzero, out);
}